// Round 1
// baseline (728.875 us; speedup 1.0000x reference)
//
#include <hip/hip_runtime.h>

// AWQ 4-bit fused dequant GEMM: out[M,N] = x[M,K] @ W[N,K]^T + bias
// W[o,i] = ((qw[o][i/8] >> 4*(i%8)) & 0xF - z[o][i/128]) * s[o][i/128]
// bf16 MFMA 16x16x32, BM=256 BN=128 BK=64, 4 waves, XOR-swizzled LDS,
// XCD-chunked block swizzle. No workspace needed.

#define BM 256
#define BN 128
#define BK 64

typedef short frag_ab __attribute__((ext_vector_type(8)));  // 8 bf16
typedef float frag_cd __attribute__((ext_vector_type(4)));  // 4 f32

__device__ __forceinline__ unsigned short f2bf(float f) {
    unsigned int u = __builtin_bit_cast(unsigned int, f);
    u += 0x7FFFu + ((u >> 16) & 1u);   // RNE
    return (unsigned short)(u >> 16);
}

__global__ __launch_bounds__(256, 2) void awq_gemm_kernel(
    const float* __restrict__ x,
    const int*   __restrict__ qw,
    const int*   __restrict__ qz,
    const float* __restrict__ sc,
    const float* __restrict__ bias,
    float*       __restrict__ out,
    int M, int N, int K)
{
    __shared__ unsigned short As[BM * BK];  // 32 KB
    __shared__ unsigned short Bs[BN * BK];  // 16 KB

    const int tid  = threadIdx.x;
    const int lane = tid & 63;
    const int wave = tid >> 6;           // 0..3
    const int wr   = wave >> 1;          // row half (128 rows)
    const int wc   = wave & 1;           // col half (64 cols)
    const int lrow = lane & 15;
    const int lko  = (lane >> 4) << 3;   // 0,8,16,24
    const int swzl = (lrow & 7) << 3;    // bank-conflict XOR (elements)

    // XCD-aware chunked swizzle: 1024 blocks -> 8 chunks of 128
    const int cpx = gridDim.x >> 3;
    const int bid = (blockIdx.x & 7) * cpx + (blockIdx.x >> 3);
    const int ntile = N / BN;            // 32
    const int bm = bid / ntile;
    const int bn = bid % ntile;
    const int m0 = bm * BM;
    const int n0 = bn * BN;

    const int ngrp = K >> 7;             // 32 groups
    const int kw   = K >> 3;             // int32 per qweight row

    const int srow = tid >> 3;           // 0..31
    const int scol = tid & 7;
    const int k0s  = scol << 3;          // 0..56

    frag_cd acc[8][4];
    #pragma unroll
    for (int m = 0; m < 8; ++m)
        #pragma unroll
        for (int n = 0; n < 4; ++n)
            #pragma unroll
            for (int e = 0; e < 4; ++e) acc[m][n][e] = 0.f;

    for (int kt = 0; kt < K; kt += BK) {
        // ---- stage A: x[m0+0..255][kt+0..63] f32 -> bf16, swizzled LDS
        #pragma unroll
        for (int t = 0; t < 8; ++t) {
            int row = srow + t * 32;
            const float* src = x + (size_t)(m0 + row) * K + kt + k0s;
            float4 a0 = *reinterpret_cast<const float4*>(src);
            float4 a1 = *reinterpret_cast<const float4*>(src + 4);
            uint4 p;
            p.x = (unsigned)f2bf(a0.x) | ((unsigned)f2bf(a0.y) << 16);
            p.y = (unsigned)f2bf(a0.z) | ((unsigned)f2bf(a0.w) << 16);
            p.z = (unsigned)f2bf(a1.x) | ((unsigned)f2bf(a1.y) << 16);
            p.w = (unsigned)f2bf(a1.z) | ((unsigned)f2bf(a1.w) << 16);
            int idx = row * BK + (k0s ^ ((row & 7) << 3));
            *reinterpret_cast<uint4*>(&As[idx]) = p;
        }
        // ---- stage B: dequant qweight rows n0+0..127, k in [kt,kt+64)
        {
            const int grp = kt >> 7;   // all 64 k of this tile in one group
            #pragma unroll
            for (int t = 0; t < 4; ++t) {
                int row = srow + t * 32;      // 0..127
                int og  = n0 + row;
                unsigned u  = (unsigned)qw[(size_t)og * kw + (kt >> 3) + scol];
                float scale = sc[og * ngrp + grp];
                unsigned zq = (unsigned)qz[og * (ngrp >> 3) + (grp >> 3)];
                float zf = (float)((zq >> ((grp & 7) << 2)) & 0xF);
                float c  = -zf * scale;       // w = q*scale + c
                unsigned short h[8];
                #pragma unroll
                for (int e = 0; e < 8; ++e) {
                    float q = (float)((u >> (e * 4)) & 0xF);
                    h[e] = f2bf(q * scale + c);
                }
                uint4 p;
                p.x = (unsigned)h[0] | ((unsigned)h[1] << 16);
                p.y = (unsigned)h[2] | ((unsigned)h[3] << 16);
                p.z = (unsigned)h[4] | ((unsigned)h[5] << 16);
                p.w = (unsigned)h[6] | ((unsigned)h[7] << 16);
                int idx = row * BK + (k0s ^ ((row & 7) << 3));
                *reinterpret_cast<uint4*>(&Bs[idx]) = p;
            }
        }
        __syncthreads();
        // ---- MFMA: 2 k-steps of 32, acc[8][4] per wave (128x64 out)
        #pragma unroll
        for (int kk = 0; kk < 2; ++kk) {
            frag_ab af[8], bfr[4];
            #pragma unroll
            for (int m = 0; m < 8; ++m) {
                int arow = wr * 128 + m * 16 + lrow;
                int idx = arow * BK + ((kk * 32 + lko) ^ swzl);
                af[m] = __builtin_bit_cast(frag_ab,
                        *reinterpret_cast<const uint4*>(&As[idx]));
            }
            #pragma unroll
            for (int n = 0; n < 4; ++n) {
                int brow = wc * 64 + n * 16 + lrow;
                int idx = brow * BK + ((kk * 32 + lko) ^ swzl);
                bfr[n] = __builtin_bit_cast(frag_ab,
                         *reinterpret_cast<const uint4*>(&Bs[idx]));
            }
            #pragma unroll
            for (int m = 0; m < 8; ++m)
                #pragma unroll
                for (int n = 0; n < 4; ++n)
                    acc[m][n] = __builtin_amdgcn_mfma_f32_16x16x32_bf16(
                        af[m], bfr[n], acc[m][n], 0, 0, 0);
        }
        __syncthreads();
    }

    // ---- epilogue: C[row = (lane>>4)*4+e, col = lane&15] per 16x16 frag
    const int r4 = (lane >> 4) << 2;
    #pragma unroll
    for (int n = 0; n < 4; ++n) {
        int col = n0 + wc * 64 + n * 16 + lrow;
        float bv = bias[col];
        #pragma unroll
        for (int m = 0; m < 8; ++m) {
            size_t rbase = (size_t)(m0 + wr * 128 + m * 16 + r4) * N + col;
            #pragma unroll
            for (int e = 0; e < 4; ++e)
                out[rbase + (size_t)e * N] = acc[m][n][e] + bv;
        }
    }
}

extern "C" void kernel_launch(void* const* d_in, const int* in_sizes, int n_in,
                              void* d_out, int out_size, void* d_ws, size_t ws_size,
                              hipStream_t stream) {
    const float* x    = (const float*)d_in[0];
    const int*   qwp  = (const int*)d_in[1];
    const int*   qzp  = (const int*)d_in[2];
    const float* scp  = (const float*)d_in[3];
    const float* bp   = (const float*)d_in[4];
    float* outp = (float*)d_out;

    const int N = in_sizes[4];                 // 4096 (O)
    const int K = (in_sizes[1] / N) * 8;       // 4096 (I)
    const int M = in_sizes[0] / K;             // 8192 (B)

    dim3 grid((M / BM) * (N / BN));            // 32*32 = 1024
    dim3 block(256);
    awq_gemm_kernel<<<grid, block, 0, stream>>>(x, qwp, qzp, scp, bp, outp, M, N, K);
}

// Round 2
// 508.106 us; speedup vs baseline: 1.4345x; 1.4345x over previous
//
#include <hip/hip_runtime.h>
#include <stdint.h>

// AWQ 4-bit fused dequant GEMM: out[M,N] = x[M,K] @ W[N,K]^T + bias
// fp16 MFMA 16x16x32, BM=128 BN=256 BK=64, 4 waves, XOR-swizzled LDS,
// 2-phase reg-prefetch pipeline, fp16 magic-number dequant,
// optional x->fp16 pre-pass into d_ws (pair-permuted packing).

#define BM 128
#define BN 256
#define BK 64

typedef _Float16 f16x2 __attribute__((ext_vector_type(2)));
typedef _Float16 f16x8 __attribute__((ext_vector_type(8)));
typedef float f32x4 __attribute__((ext_vector_type(4)));

// ---- pre-pass: x f32 -> fp16, packed as pair-permuted u32 words:
// chunk j (8 elems), word i = (f16(x[8j+i]) | f16(x[8j+4+i])<<16), i=0..3
__global__ void convert_x_kernel(const float4* __restrict__ x,
                                 uint4* __restrict__ xh, int nchunk) {
    int i = blockIdx.x * blockDim.x + threadIdx.x;
    if (i >= nchunk) return;
    float4 f0 = x[2 * i], f1 = x[2 * i + 1];
    uint4 o;
    o.x = __builtin_bit_cast(uint32_t, __builtin_amdgcn_cvt_pkrtz(f0.x, f1.x));
    o.y = __builtin_bit_cast(uint32_t, __builtin_amdgcn_cvt_pkrtz(f0.y, f1.y));
    o.z = __builtin_bit_cast(uint32_t, __builtin_amdgcn_cvt_pkrtz(f0.z, f1.z));
    o.w = __builtin_bit_cast(uint32_t, __builtin_amdgcn_cvt_pkrtz(f0.w, f1.w));
    xh[i] = o;
}

template <bool USEWS>
__global__ __launch_bounds__(256, 2) void awq_gemm_kernel(
    const float* __restrict__ x,
    const uint32_t* __restrict__ xh,
    const int* __restrict__ qw,
    const int* __restrict__ qz,
    const float* __restrict__ sc,
    const float* __restrict__ bias,
    float* __restrict__ out,
    int M, int N, int K)
{
    __shared__ __align__(16) unsigned short As[BM * BK];  // 16 KB
    __shared__ __align__(16) unsigned short Bs[BN * BK];  // 32 KB

    const int tid  = threadIdx.x;
    const int lane = tid & 63;
    const int wave = tid >> 6;           // 0..3
    const int wr   = wave >> 1;          // row half (64 rows each)
    const int wc   = wave & 1;           // col half (128 cols each)
    const int lrow = lane & 15;
    const int lko  = (lane >> 4) << 3;   // chunk offset 0,8,16,24

    // XCD-aware chunked swizzle (1024 blocks, %8==0 -> bijective)
    const int cpx = gridDim.x >> 3;
    const int bid = (blockIdx.x & 7) * cpx + (blockIdx.x >> 3);
    const int ntn = N / BN;              // 16
    const int m0 = (bid / ntn) * BM;
    const int n0 = (bid % ntn) * BN;

    const int ngrp = K >> 7;             // 32
    const int nzw  = ngrp >> 3;          // 4
    const int kw   = K >> 3;             // int32 per qweight row
    const int NT   = K / BK;             // 64

    // staging thread maps
    const int r_a = tid >> 1;            // 0..127 (A row)
    const int kh  = tid & 1;             // which 32-k half
    const int r_b = tid;                 // 0..255 (B row)
    const int swa = (r_a & 7) << 3;
    const int swb = (r_b & 7) << 3;

    f32x4 acc[4][8];
    #pragma unroll
    for (int m = 0; m < 4; ++m)
        #pragma unroll
        for (int n = 0; n < 8; ++n)
            #pragma unroll
            for (int e = 0; e < 4; ++e) acc[m][n][e] = 0.f;

    // prefetch registers
    float4 a32[8];
    uint4  a16[4];
    uint32_t bq[8];
    float bs;
    uint32_t bz;

    auto LOADA = [&](int kt) {
        if constexpr (USEWS) {
            const uint32_t* p = xh + ((size_t)(m0 + r_a) * K + kt + kh * 32) / 2;
            #pragma unroll
            for (int i = 0; i < 4; ++i)
                a16[i] = *reinterpret_cast<const uint4*>(p + 4 * i);
        } else {
            const float* p = x + (size_t)(m0 + r_a) * K + kt + kh * 32;
            #pragma unroll
            for (int i = 0; i < 8; ++i)
                a32[i] = *reinterpret_cast<const float4*>(p + 4 * i);
        }
    };
    auto LOADB = [&](int kt) {
        const int4* p = reinterpret_cast<const int4*>(qw + (size_t)(n0 + r_b) * kw + (kt >> 3));
        *reinterpret_cast<int4*>(&bq[0]) = p[0];
        *reinterpret_cast<int4*>(&bq[4]) = p[1];
        int grp = kt >> 7;
        bs = sc[(size_t)(n0 + r_b) * ngrp + grp];
        bz = ((uint32_t)qz[(size_t)(n0 + r_b) * nzw + (grp >> 3)] >> ((grp & 7) << 2)) & 0xF;
    };
    auto WRITEA = [&]() {
        #pragma unroll
        for (int i = 0; i < 4; ++i) {
            int kcol = kh * 32 + 8 * i;
            int idx = r_a * BK + (kcol ^ swa);
            if constexpr (USEWS) {
                *reinterpret_cast<uint4*>(&As[idx]) = a16[i];
            } else {
                uint4 o;
                o.x = __builtin_bit_cast(uint32_t, __builtin_amdgcn_cvt_pkrtz(a32[2*i].x, a32[2*i+1].x));
                o.y = __builtin_bit_cast(uint32_t, __builtin_amdgcn_cvt_pkrtz(a32[2*i].y, a32[2*i+1].y));
                o.z = __builtin_bit_cast(uint32_t, __builtin_amdgcn_cvt_pkrtz(a32[2*i].z, a32[2*i+1].z));
                o.w = __builtin_bit_cast(uint32_t, __builtin_amdgcn_cvt_pkrtz(a32[2*i].w, a32[2*i+1].w));
                *reinterpret_cast<uint4*>(&As[idx]) = o;
            }
        }
    };
    auto WRITEB = [&]() {
        _Float16 hs = (_Float16)bs;
        _Float16 hz = (_Float16)(1024.0f + (float)bz);   // integer <=1039: exact in fp16
        f16x2 s2 = {hs, hs};
        f16x2 z2 = {hz, hz};
        const uint32_t MK = 0x000F000Fu, MG = 0x64006400u;
        #pragma unroll
        for (int j = 0; j < 8; ++j) {
            uint32_t u = bq[j];
            uint32_t t0 = (u & MK) | MG;
            uint32_t t1 = ((u >> 4) & MK) | MG;
            uint32_t t2 = ((u >> 8) & MK) | MG;
            uint32_t t3 = ((u >> 12) & MK) | MG;
            // (1024+q) - (1024+z) is exact; then * s
            f16x2 w0 = (__builtin_bit_cast(f16x2, t0) - z2) * s2;
            f16x2 w1 = (__builtin_bit_cast(f16x2, t1) - z2) * s2;
            f16x2 w2 = (__builtin_bit_cast(f16x2, t2) - z2) * s2;
            f16x2 w3 = (__builtin_bit_cast(f16x2, t3) - z2) * s2;
            uint4 o;
            o.x = __builtin_bit_cast(uint32_t, w0);
            o.y = __builtin_bit_cast(uint32_t, w1);
            o.z = __builtin_bit_cast(uint32_t, w2);
            o.w = __builtin_bit_cast(uint32_t, w3);
            int kcol = 8 * j;
            int idx = r_b * BK + (kcol ^ swb);
            *reinterpret_cast<uint4*>(&Bs[idx]) = o;
        }
    };

    LOADA(0); LOADB(0);

    for (int t = 0; t < NT; ++t) {
        WRITEA();
        WRITEB();
        __syncthreads();
        if (t + 1 < NT) { LOADA((t + 1) * BK); LOADB((t + 1) * BK); }
        // MFMA phase: 2 k-steps of 32
        #pragma unroll
        for (int kk = 0; kk < 2; ++kk) {
            f16x8 af[4], bf[8];
            #pragma unroll
            for (int m = 0; m < 4; ++m) {
                int arow = wr * 64 + m * 16 + lrow;
                int idx = arow * BK + ((kk * 32 + lko) ^ ((arow & 7) << 3));
                af[m] = __builtin_bit_cast(f16x8,
                        *reinterpret_cast<const uint4*>(&As[idx]));
            }
            #pragma unroll
            for (int n = 0; n < 8; ++n) {
                int brow = wc * 128 + n * 16 + lrow;
                int idx = brow * BK + ((kk * 32 + lko) ^ ((brow & 7) << 3));
                bf[n] = __builtin_bit_cast(f16x8,
                        *reinterpret_cast<const uint4*>(&Bs[idx]));
            }
            #pragma unroll
            for (int m = 0; m < 4; ++m)
                #pragma unroll
                for (int n = 0; n < 8; ++n)
                    acc[m][n] = __builtin_amdgcn_mfma_f32_16x16x32_f16(
                        af[m], bf[n], acc[m][n], 0, 0, 0);
        }
        __syncthreads();
    }

    // epilogue: C frag mapping col=lane&15, row=(lane>>4)*4+e
    const int r4 = (lane >> 4) << 2;
    #pragma unroll
    for (int n = 0; n < 8; ++n) {
        int col = n0 + wc * 128 + n * 16 + lrow;
        float bv = bias[col];
        #pragma unroll
        for (int m = 0; m < 4; ++m) {
            size_t rbase = (size_t)(m0 + wr * 64 + m * 16 + r4) * N + col;
            #pragma unroll
            for (int e = 0; e < 4; ++e)
                out[rbase + (size_t)e * N] = acc[m][n][e] + bv;
        }
    }
}

extern "C" void kernel_launch(void* const* d_in, const int* in_sizes, int n_in,
                              void* d_out, int out_size, void* d_ws, size_t ws_size,
                              hipStream_t stream) {
    const float* x   = (const float*)d_in[0];
    const int*   qwp = (const int*)d_in[1];
    const int*   qzp = (const int*)d_in[2];
    const float* scp = (const float*)d_in[3];
    const float* bp  = (const float*)d_in[4];
    float* outp = (float*)d_out;

    const int N = in_sizes[4];                 // 4096 (O)
    const int K = (in_sizes[1] / N) * 8;       // 4096 (I)
    const int M = in_sizes[0] / K;             // 8192 (B)

    dim3 grid((M / BM) * (N / BN));            // 64*16 = 1024
    dim3 block(256);

    const size_t need = (size_t)M * K * 2;
    if (ws_size >= need) {
        uint32_t* xh = (uint32_t*)d_ws;
        int nchunk = (M * (K / 8));
        convert_x_kernel<<<dim3((nchunk + 255) / 256), dim3(256), 0, stream>>>(
            (const float4*)x, (uint4*)xh, nchunk);
        awq_gemm_kernel<true><<<grid, block, 0, stream>>>(
            x, xh, qwp, qzp, scp, bp, outp, M, N, K);
    } else {
        awq_gemm_kernel<false><<<grid, block, 0, stream>>>(
            x, nullptr, qwp, qzp, scp, bp, outp, M, N, K);
    }
}